// Round 19
// baseline (265.353 us; speedup 1.0000x reference)
//
#include <hip/hip_runtime.h>
#include <hip/hip_bf16.h>
#include <hip/hip_fp16.h>
#include <math.h>

typedef unsigned short u16;
typedef unsigned int u32;
typedef unsigned long long u64;
typedef __attribute__((ext_vector_type(8))) short bf16x8;
typedef __attribute__((ext_vector_type(4))) float f32x4;

#define N_NODES 8192
#define DIM 512
#define KSEL 31
#define BANDCAP 128
#define SEG_SIZE 2048
#define NVALID 6144   // cross-segment columns per row
#define BAND_ULP 8    // band half-width in f16 ulps (R14..R18-verified)

// monotone 16-bit key from f16 bits (larger key <=> larger value)
__device__ __forceinline__ u32 f16key(u32 h) {
  return (h & 0x8000u) ? (0xFFFFu & ~h) : (h | 0x8000u);
}
__device__ __forceinline__ u32 packkeys(u32 w) {  // two f16 -> two keys
  return f16key(w & 0xFFFFu) | (f16key(w >> 16) << 16);
}
__device__ __forceinline__ float keyval(u32 k) {
  const u16 raw = (k & 0x8000u) ? (u16)(k ^ 0x8000u) : (u16)(~k & 0xFFFFu);
  __half_raw hr; hr.x = raw;
  return __half2float(__half(hr));
}

#define GLD_LDS16(g, l)                                        \
  __builtin_amdgcn_global_load_lds(                            \
      (const __attribute__((address_space(1))) void*)(g),      \
      (__attribute__((address_space(3))) void*)(l), 16, 0, 0)

// ---------------------------------------------------------------------------
// Kernel 1: emb replicating numpy-f32 bit-exactly (verified R6). Also zeroes
// the per-row kmax accumulator used by the gemm epilogue.
// ---------------------------------------------------------------------------
__global__ __launch_bounds__(256) void prep_kernel(
    const float* __restrict__ feat, const float* __restrict__ w0,
    const float* __restrict__ w1, u16* __restrict__ embh,
    float* __restrict__ embf, u32* __restrict__ kmax32) {
#pragma clang fp contract(off)
  const int row = blockIdx.x;
  const int t = threadIdx.x;
  __shared__ float hs[DIM];
  __shared__ float partial[32];
  __shared__ float rinv_sh;

  const float2 x = *reinterpret_cast<const float2*>(feat + (size_t)row * DIM + t * 2);
  const float2 a = *reinterpret_cast<const float2*>(w0 + t * 2);
  const float2 b = *reinterpret_cast<const float2*>(w1 + t * 2);
  const float h0 = fmaxf(x.x * a.x, 0.0f) * b.x;
  const float h1 = fmaxf(x.y * a.y, 0.0f) * b.y;
  hs[t * 2] = h0;
  hs[t * 2 + 1] = h1;
  if (t == 0) kmax32[row] = 0u;
  __syncthreads();

  if (t < 32) {
    const int base = (t >> 3) * 128 + (t & 7);
    float v = hs[base];
    float acc = v * v;
    for (int i = 1; i < 16; ++i) {
      v = hs[base + 8 * i];
      const float vv = v * v;
      acc = acc + vv;
    }
    partial[t] = acc;
  }
  __syncthreads();
  if (t == 0) {
    float B[4];
    for (int blk = 0; blk < 4; ++blk) {
      const float* p = &partial[blk * 8];
      B[blk] = ((p[0] + p[1]) + (p[2] + p[3])) + ((p[4] + p[5]) + (p[6] + p[7]));
    }
    const float s = (B[0] + B[1]) + (B[2] + B[3]);
    const float sp = s + 1e-24f;
    const float qf = (float)sqrt((double)sp);
    rinv_sh = (float)(1.0 / (double)qf);
  }
  __syncthreads();
  const float rinv = rinv_sh;
  const float e0 = h0 * rinv;
  const float e1 = h1 * rinv;
  *reinterpret_cast<float2*>(embf + (size_t)row * DIM + t * 2) = make_float2(e0, e1);
  __hip_bfloat162 bb;
  bb.x = __float2bfloat16(e0);
  bb.y = __float2bfloat16(e1);
  *reinterpret_cast<__hip_bfloat162*>(embh + (size_t)row * DIM + t * 2) = bb;
}

// ---------------------------------------------------------------------------
// Kernel 2: ranking sim (bf16 MFMA) -> f16, packed cross-seg columns.
// Epilogue accumulates per-row max (monotone f32-key atomicMax).
// ---------------------------------------------------------------------------
__global__ __launch_bounds__(256) void gemm_kernel(const u16* __restrict__ embh,
                                                   __half* __restrict__ simh,
                                                   u32* __restrict__ kmax32) {
  __shared__ u16 As[128][64];
  __shared__ u16 Bs[128][64];
  const int tid = threadIdx.x;
  const int lane = tid & 63;
  const int wave = tid >> 6;
  const int wm = wave >> 1;
  const int wn = wave & 1;
  const int rowTile = blockIdx.y;
  const int segTileBase = (rowTile >> 4) << 4;
  const int cT = blockIdx.x;
  const int colTile = cT < segTileBase ? cT : cT + 16;
  const int row0 = rowTile * 128;
  const int col0 = colTile * 128;

  f32x4 acc[4][4] = {};

  for (int k0 = 0; k0 < DIM; k0 += 64) {
#pragma unroll
    for (int i = 0; i < 4; ++i) {
      const int flat = i * 256 + tid;
      const int r = flat >> 3;
      const int c = (flat & 7) * 8;
      GLD_LDS16(embh + (size_t)(row0 + r) * DIM + k0 + c, &As[r][c]);
      GLD_LDS16(embh + (size_t)(col0 + r) * DIM + k0 + c, &Bs[r][c]);
    }
    __syncthreads();
#pragma unroll
    for (int kk = 0; kk < 2; ++kk) {
      bf16x8 afr[4], bfr[4];
      const int koff = kk * 32 + (lane >> 4) * 8;
      const int rsel = lane & 15;
#pragma unroll
      for (int m = 0; m < 4; ++m)
        afr[m] = *reinterpret_cast<const bf16x8*>(&As[wm * 64 + m * 16 + rsel][koff]);
#pragma unroll
      for (int n = 0; n < 4; ++n)
        bfr[n] = *reinterpret_cast<const bf16x8*>(&Bs[wn * 64 + n * 16 + rsel][koff]);
#pragma unroll
      for (int m = 0; m < 4; ++m)
#pragma unroll
        for (int n = 0; n < 4; ++n)
          acc[m][n] = __builtin_amdgcn_mfma_f32_16x16x32_bf16(afr[m], bfr[n],
                                                              acc[m][n], 0, 0, 0);
    }
    __syncthreads();
  }
#pragma unroll
  for (int m = 0; m < 4; ++m)
#pragma unroll
    for (int n = 0; n < 4; ++n)
#pragma unroll
      for (int j = 0; j < 4; ++j) {
        const int r = row0 + wm * 64 + m * 16 + (lane >> 4) * 4 + j;
        const int pcol = cT * 128 + wn * 64 + n * 16 + (lane & 15);
        simh[(size_t)r * NVALID + pcol] = __float2half(acc[m][n][j]);
      }
  // per-row max over this tile -> global atomicMax (monotone f32 key)
#pragma unroll
  for (int m = 0; m < 4; ++m) {
#pragma unroll
    for (int j = 0; j < 4; ++j) {
      float vmax = fmaxf(fmaxf(acc[m][0][j], acc[m][1][j]),
                         fmaxf(acc[m][2][j], acc[m][3][j]));
#pragma unroll
      for (int off = 1; off < 16; off <<= 1)
        vmax = fmaxf(vmax, __shfl_xor(vmax, off, 64));
      if ((lane & 15) == 0) {
        const int r = row0 + wm * 64 + m * 16 + (lane >> 4) * 4 + j;
        const u32 b = __float_as_uint(vmax);
        const u32 kk = (b & 0x80000000u) ? ~b : (b | 0x80000000u);
        atomicMax(&kmax32[r], kk);
      }
    }
  }
}

// ---------------------------------------------------------------------------
// Kernel 3: block-per-4-rows select (R18 semantics), optionally fused with
// the output-row write (FUSED=true when simh lives in d_ws). Register-
// resident keys; tail-window interval sandwich; band resolved by bit-exact
// np-sequential dots (verified R6).
// ---------------------------------------------------------------------------
template <bool FUSED>
__global__ __launch_bounds__(256) void select_kernel(
    const __half* __restrict__ simh, const float* __restrict__ embf,
    const u32* __restrict__ kmax32, int2* __restrict__ compact,
    float* __restrict__ out) {
  const int t = threadIdx.x;
  const int lane = t & 63;
  const int wave = t >> 6;

  __shared__ u32 hist[257];
  __shared__ int bcol[BANDCAP];
  __shared__ float bex[BANDCAP];
  __shared__ int outidx_s[KSEL];
  __shared__ float outval_s[KSEL];
  __shared__ int cnts[2];          // [0]=band count, [1]=out count
  __shared__ u32 sh_lo, sh_hi, sh_need;
  __shared__ int sh_state;         // 0=escalate, 1=descend, 2=done

  for (int rr = 0; rr < 4; ++rr) {
    const int row = blockIdx.x * 4 + rr;
    const int segBase = (row >> 11) << 11;

    // load row once: 3 uint4/thread, pack keys in place (12 VGPRs)
    u32 pk[12];
    {
      const uint4* src = reinterpret_cast<const uint4*>(simh + (size_t)row * NVALID);
      const uint4 a = src[t], b = src[256 + t], c = src[512 + t];
      pk[0] = packkeys(a.x); pk[1] = packkeys(a.y);
      pk[2] = packkeys(a.z); pk[3] = packkeys(a.w);
      pk[4] = packkeys(b.x); pk[5] = packkeys(b.y);
      pk[6] = packkeys(b.z); pk[7] = packkeys(b.w);
      pk[8] = packkeys(c.x); pk[9] = packkeys(c.y);
      pk[10] = packkeys(c.z); pk[11] = packkeys(c.w);
    }
#define KEY(v) ((pk[(v) >> 1] >> (((v) & 1) * 16)) & 0xFFFFu)
#define COL(v) ((((((v) >> 3) * 256) + t) << 3) + ((v) & 7))

    if (t < KSEL) { outidx_s[t] = segBase; outval_s[t] = 0.0f; }
    if (t == 0) { cnts[0] = 0; cnts[1] = 0; }

    // row-max f16 key from gemm's f32-key accumulator (RTN monotone)
    u32 kmax16;
    {
      const u32 kk = kmax32[row];
      const u32 fb = (kk & 0x80000000u) ? (kk ^ 0x80000000u) : ~kk;
      const __half h = __float2half(__uint_as_float(fb));
      kmax16 = f16key((u32)__half_as_ushort(h));
    }

    // locate interval [binlo, binhi] containing the 31st-largest key
    u32 base = (kmax16 > 511u) ? kmax16 - 511u : 0u;
    u32 winTop = kmax16;
    u32 shift = 2;
    u32 need = KSEL;
    int tier = 0;
    for (int guard = 0; guard < 6; ++guard) {
      hist[t] = 0;
      if (t == 0) hist[256] = 0;
      __syncthreads();
#pragma unroll
      for (int v = 0; v < 24; ++v) {
        const u32 k = KEY(v);
        if (k >= base && k <= winTop) atomicAdd(&hist[(k - base) >> shift], 1u);
      }
      __syncthreads();
      if (wave == 0) {
        const int x = lane * 4;
        const u32 b0 = hist[x], b1 = hist[x + 1];
        const u32 b2 = hist[x + 2], b3 = hist[x + 3];
        const u32 tot = b0 + b1 + b2 + b3;
        u32 inc = tot;
#pragma unroll
        for (int off = 1; off < 64; off <<= 1) {
          const u32 vv = (u32)__shfl_down((int)inc, off, 64);
          if (lane + off < 64) inc += vv;
        }
        const u32 exc = inc - tot;
        const u32 g3 = exc, g2 = g3 + b3, g1 = g2 + b2, g0 = g1 + b1;
        int sel = -1;
        u32 gsel = 0;
        if (g3 < need && g3 + b3 >= need) { sel = x + 3; gsel = g3; }
        else if (g2 < need && g2 + b2 >= need) { sel = x + 2; gsel = g2; }
        else if (g1 < need && g1 + b1 >= need) { sel = x + 1; gsel = g1; }
        else if (g0 < need && g0 + b0 >= need) { sel = x;     gsel = g0; }
        const u64 bal = __ballot(sel >= 0);
        if (lane == 0 && bal == 0) sh_state = 0;  // escalate
        if (bal != 0) {
          const int srcl = (int)(__ffsll((unsigned long long)bal) - 1);
          sel  = __shfl(sel, srcl, 64);
          gsel = (u32)__shfl((int)gsel, srcl, 64);
          if (lane == 0) {
            const u32 blo = base + ((u32)sel << shift);
            const u32 bhi = min(blo + (1u << shift) - 1u, winTop);
            sh_lo = blo; sh_hi = bhi; sh_need = need - gsel;
            sh_state = (shift > 2) ? 1 : 2;
          }
        }
      }
      __syncthreads();
      const int st = sh_state;
      if (st == 2) break;
      if (st == 1) {  // descend into wide bin with 1-ulp bins
        base = sh_lo; winTop = sh_hi; shift = 0; need = sh_need;
      } else {        // escalate window
        ++tier;
        if (tier == 1) { base = (kmax16 > 8191u) ? kmax16 - 8191u : 0u; shift = 5; }
        else { base = 0u; shift = 8; }
        winTop = kmax16; need = KSEL;
      }
      __syncthreads();
    }
    const u32 binlo = sh_lo, binhi = sh_hi;
    const u32 hiK = binhi + BAND_ULP;
    const u32 loK = (binlo >= BAND_ULP) ? binlo - BAND_ULP : 0u;

    // classify from regs: emit H (f16 value), collect band cols
#pragma unroll
    for (int v = 0; v < 24; ++v) {
      const u32 k = KEY(v);
      if (k > hiK) {
        const int slot = atomicAdd(&cnts[1], 1);
        const int i = COL(v);
        if (slot < KSEL) {
          outidx_s[slot] = (i < segBase) ? i : i + SEG_SIZE;
          outval_s[slot] = fmaxf(keyval(k), 0.0f);
        }
      } else if (k >= loK) {
        const int slot = atomicAdd(&cnts[0], 1);
        const int i = COL(v);
        if (slot < BANDCAP) bcol[slot] = (i < segBase) ? i : i + SEG_SIZE;
      }
    }
    __syncthreads();
    const int nH = min(cnts[1], KSEL);
    const int slots = KSEL - nH;
    const int nB = min(cnts[0], BANDCAP);

    // bit-exact np-sequential dots for band members (verified R6 rounding)
    if (t < nB) {
#pragma clang fp contract(off)
      const float4* g4 =
          reinterpret_cast<const float4*>(embf + (size_t)bcol[t] * DIM);
      const float4* e4 = reinterpret_cast<const float4*>(embf + (size_t)row * DIM);
      float acc = 0.0f;
      for (int k4 = 0; k4 < DIM / 4; ++k4) {
        const float4 a = e4[k4];
        const float4 b = g4[k4];
        acc = acc + a.x * b.x;
        acc = acc + a.y * b.y;
        acc = acc + a.z * b.z;
        acc = acc + a.w * b.w;
      }
      bex[t] = acc;
    }
    __syncthreads();

    // band rank (exact desc, col asc); winners fill remaining slots
    if (t < nB) {
      const float ev = bex[t];
      const int ec = bcol[t];
      int r = 0;
      for (int j = 0; j < nB; ++j) {
        const float oj = bex[j];
        const int cj = bcol[j];
        if (oj > ev || (oj == ev && cj < ec)) r++;
      }
      if (r < slots) {
        const int slot = atomicAdd(&cnts[1], 1);
        if (slot < KSEL) { outidx_s[slot] = ec; outval_s[slot] = fmaxf(ev, 0.0f); }
      }
    }
    __syncthreads();

    if constexpr (FUSED) {
      // write the output row directly: zeros + scatter
      float* orow = out + (size_t)row * N_NODES;
      const float4 zero4 = make_float4(0.f, 0.f, 0.f, 0.f);
#pragma unroll
      for (int i = 0; i < 8; ++i)
        reinterpret_cast<float4*>(orow)[i * 256 + t] = zero4;
      __syncthreads();
      if (t < KSEL) orow[outidx_s[t]] = outval_s[t];
    } else {
      if (t < KSEL)
        compact[(size_t)row * KSEL + t] =
            make_int2(outidx_s[t], __float_as_int(outval_s[t]));
    }
    __syncthreads();  // LDS reuse fence before next row
#undef KEY
#undef COL
  }
}

// ---------------------------------------------------------------------------
// Kernel 4 (fallback path only): streaming writer — zero row, scatter 31.
// ---------------------------------------------------------------------------
__global__ __launch_bounds__(256) void write_kernel(
    const int2* __restrict__ compact, float* __restrict__ out) {
  const int row = blockIdx.x;
  const int t = threadIdx.x;
  __shared__ int sidx[KSEL];
  __shared__ float sval[KSEL];
  if (t < KSEL) {
    const int2 e = compact[(size_t)row * KSEL + t];
    sidx[t] = e.x;
    sval[t] = __int_as_float(e.y);
  }
  float* orow = out + (size_t)row * N_NODES;
  const float4 zero4 = make_float4(0.f, 0.f, 0.f, 0.f);
  __syncthreads();
#pragma unroll
  for (int i = 0; i < 8; ++i)
    reinterpret_cast<float4*>(orow)[i * 256 + t] = zero4;
  __syncthreads();
  if (t < KSEL) orow[sidx[t]] = sval[t];
}

// ---------------------------------------------------------------------------
extern "C" void kernel_launch(void* const* d_in, const int* in_sizes, int n_in,
                              void* d_out, int out_size, void* d_ws, size_t ws_size,
                              hipStream_t stream) {
  const float* feat = (const float*)d_in[0];
  const float* w0 = (const float*)d_in[1];
  const float* w1 = (const float*)d_in[2];
  float* out = (float*)d_out;

  u16* embh = (u16*)d_ws;                                           // [0,8MiB)
  float* embf = (float*)((char*)d_ws + (size_t)N_NODES * DIM * 2);  // [8,24MiB)
  u32* kmax32 = (u32*)((char*)d_ws + (size_t)24 * 1024 * 1024);     // 32 KiB
  int2* compact = (int2*)d_ws;                                      // reuses embh

  const size_t simh_off = (size_t)32 * 1024 * 1024;
  const size_t simh_bytes = (size_t)N_NODES * NVALID * 2;           // 96 MiB
  const bool fused = ws_size >= simh_off + simh_bytes;
  __half* simh = fused ? (__half*)((char*)d_ws + simh_off) : (__half*)d_out;

  prep_kernel<<<N_NODES, 256, 0, stream>>>(feat, w0, w1, embh, embf, kmax32);
  dim3 grid(48, 64);
  gemm_kernel<<<grid, 256, 0, stream>>>(embh, simh, kmax32);
  if (fused) {
    select_kernel<true><<<N_NODES / 4, 256, 0, stream>>>(simh, embf, kmax32,
                                                         compact, out);
  } else {
    select_kernel<false><<<N_NODES / 4, 256, 0, stream>>>(simh, embf, kmax32,
                                                          compact, out);
    write_kernel<<<N_NODES, 256, 0, stream>>>(compact, out);
  }
}

// Round 20
// 258.428 us; speedup vs baseline: 1.0268x; 1.0268x over previous
//
#include <hip/hip_runtime.h>
#include <hip/hip_bf16.h>
#include <hip/hip_fp16.h>
#include <math.h>

typedef unsigned short u16;
typedef unsigned int u32;
typedef unsigned long long u64;
typedef __attribute__((ext_vector_type(8))) short bf16x8;
typedef __attribute__((ext_vector_type(4))) float f32x4;

#define N_NODES 8192
#define DIM 512
#define KSEL 31
#define BANDCAP 128
#define SEG_SIZE 2048
#define NVALID 6144   // cross-segment columns per row
#define BAND_ULP 8    // band half-width in f16 ulps (R14..R18-verified)

// monotone 16-bit key from f16 bits (larger key <=> larger value)
__device__ __forceinline__ u32 f16key(u32 h) {
  return (h & 0x8000u) ? (0xFFFFu & ~h) : (h | 0x8000u);
}
__device__ __forceinline__ u32 packkeys(u32 w) {  // two f16 -> two keys
  return f16key(w & 0xFFFFu) | (f16key(w >> 16) << 16);
}
__device__ __forceinline__ float keyval(u32 k) {
  const u16 raw = (k & 0x8000u) ? (u16)(k ^ 0x8000u) : (u16)(~k & 0xFFFFu);
  __half_raw hr; hr.x = raw;
  return __half2float(__half(hr));
}

#define GLD_LDS16(g, l)                                        \
  __builtin_amdgcn_global_load_lds(                            \
      (const __attribute__((address_space(1))) void*)(g),      \
      (__attribute__((address_space(3))) void*)(l), 16, 0, 0)

// ---------------------------------------------------------------------------
// Kernel 1: emb replicating numpy-f32 bit-exactly (verified R6). Also zeroes
// the per-row kmax accumulator used by the gemm epilogue.
// ---------------------------------------------------------------------------
__global__ __launch_bounds__(256) void prep_kernel(
    const float* __restrict__ feat, const float* __restrict__ w0,
    const float* __restrict__ w1, u16* __restrict__ embh,
    float* __restrict__ embf, u32* __restrict__ kmax32) {
#pragma clang fp contract(off)
  const int row = blockIdx.x;
  const int t = threadIdx.x;
  __shared__ float hs[DIM];
  __shared__ float partial[32];
  __shared__ float rinv_sh;

  const float2 x = *reinterpret_cast<const float2*>(feat + (size_t)row * DIM + t * 2);
  const float2 a = *reinterpret_cast<const float2*>(w0 + t * 2);
  const float2 b = *reinterpret_cast<const float2*>(w1 + t * 2);
  const float h0 = fmaxf(x.x * a.x, 0.0f) * b.x;
  const float h1 = fmaxf(x.y * a.y, 0.0f) * b.y;
  hs[t * 2] = h0;
  hs[t * 2 + 1] = h1;
  if (t == 0) kmax32[row] = 0u;
  __syncthreads();

  if (t < 32) {
    const int base = (t >> 3) * 128 + (t & 7);
    float v = hs[base];
    float acc = v * v;
    for (int i = 1; i < 16; ++i) {
      v = hs[base + 8 * i];
      const float vv = v * v;
      acc = acc + vv;
    }
    partial[t] = acc;
  }
  __syncthreads();
  if (t == 0) {
    float B[4];
    for (int blk = 0; blk < 4; ++blk) {
      const float* p = &partial[blk * 8];
      B[blk] = ((p[0] + p[1]) + (p[2] + p[3])) + ((p[4] + p[5]) + (p[6] + p[7]));
    }
    const float s = (B[0] + B[1]) + (B[2] + B[3]);
    const float sp = s + 1e-24f;
    const float qf = (float)sqrt((double)sp);
    rinv_sh = (float)(1.0 / (double)qf);
  }
  __syncthreads();
  const float rinv = rinv_sh;
  const float e0 = h0 * rinv;
  const float e1 = h1 * rinv;
  *reinterpret_cast<float2*>(embf + (size_t)row * DIM + t * 2) = make_float2(e0, e1);
  __hip_bfloat162 bb;
  bb.x = __float2bfloat16(e0);
  bb.y = __float2bfloat16(e1);
  *reinterpret_cast<__hip_bfloat162*>(embh + (size_t)row * DIM + t * 2) = bb;
}

// ---------------------------------------------------------------------------
// Kernel 2: ranking sim (bf16 MFMA) -> f16, packed cross-seg columns.
// Epilogue accumulates per-row max (monotone f32-key atomicMax).
// ---------------------------------------------------------------------------
__global__ __launch_bounds__(256) void gemm_kernel(const u16* __restrict__ embh,
                                                   __half* __restrict__ simh,
                                                   u32* __restrict__ kmax32) {
  __shared__ u16 As[128][64];
  __shared__ u16 Bs[128][64];
  const int tid = threadIdx.x;
  const int lane = tid & 63;
  const int wave = tid >> 6;
  const int wm = wave >> 1;
  const int wn = wave & 1;
  const int rowTile = blockIdx.y;
  const int segTileBase = (rowTile >> 4) << 4;
  const int cT = blockIdx.x;
  const int colTile = cT < segTileBase ? cT : cT + 16;
  const int row0 = rowTile * 128;
  const int col0 = colTile * 128;

  f32x4 acc[4][4] = {};

  for (int k0 = 0; k0 < DIM; k0 += 64) {
#pragma unroll
    for (int i = 0; i < 4; ++i) {
      const int flat = i * 256 + tid;
      const int r = flat >> 3;
      const int c = (flat & 7) * 8;
      GLD_LDS16(embh + (size_t)(row0 + r) * DIM + k0 + c, &As[r][c]);
      GLD_LDS16(embh + (size_t)(col0 + r) * DIM + k0 + c, &Bs[r][c]);
    }
    __syncthreads();
#pragma unroll
    for (int kk = 0; kk < 2; ++kk) {
      bf16x8 afr[4], bfr[4];
      const int koff = kk * 32 + (lane >> 4) * 8;
      const int rsel = lane & 15;
#pragma unroll
      for (int m = 0; m < 4; ++m)
        afr[m] = *reinterpret_cast<const bf16x8*>(&As[wm * 64 + m * 16 + rsel][koff]);
#pragma unroll
      for (int n = 0; n < 4; ++n)
        bfr[n] = *reinterpret_cast<const bf16x8*>(&Bs[wn * 64 + n * 16 + rsel][koff]);
#pragma unroll
      for (int m = 0; m < 4; ++m)
#pragma unroll
        for (int n = 0; n < 4; ++n)
          acc[m][n] = __builtin_amdgcn_mfma_f32_16x16x32_bf16(afr[m], bfr[n],
                                                              acc[m][n], 0, 0, 0);
    }
    __syncthreads();
  }
#pragma unroll
  for (int m = 0; m < 4; ++m)
#pragma unroll
    for (int n = 0; n < 4; ++n)
#pragma unroll
      for (int j = 0; j < 4; ++j) {
        const int r = row0 + wm * 64 + m * 16 + (lane >> 4) * 4 + j;
        const int pcol = cT * 128 + wn * 64 + n * 16 + (lane & 15);
        simh[(size_t)r * NVALID + pcol] = __float2half(acc[m][n][j]);
      }
  // per-row max over this tile -> global atomicMax (monotone f32 key)
#pragma unroll
  for (int m = 0; m < 4; ++m) {
#pragma unroll
    for (int j = 0; j < 4; ++j) {
      float vmax = fmaxf(fmaxf(acc[m][0][j], acc[m][1][j]),
                         fmaxf(acc[m][2][j], acc[m][3][j]));
#pragma unroll
      for (int off = 1; off < 16; off <<= 1)
        vmax = fmaxf(vmax, __shfl_xor(vmax, off, 64));
      if ((lane & 15) == 0) {
        const int r = row0 + wm * 64 + m * 16 + (lane >> 4) * 4 + j;
        const u32 b = __float_as_uint(vmax);
        const u32 kk = (b & 0x80000000u) ? ~b : (b | 0x80000000u);
        atomicMax(&kmax32[r], kk);
      }
    }
  }
}

// ---------------------------------------------------------------------------
// Kernel 3: block-per-row select (R18 structure), NARROW-window 1-ulp-bin
// histogram: tier0 [kmax-255,kmax] shift=0 (~60-120 in-window keys, no hot
// bins, single pass -> exact k31). Escalate [kmax-2047] 8-ulp + descend,
// then full range. H = {k > k31+8} emits f16 value; band [k31-8,k31+8]
// resolved by bit-exact np-sequential dots (verified R6); when nB==slots the
// whole band is in (skip dots).
// ---------------------------------------------------------------------------
__global__ __launch_bounds__(256) void select_kernel(
    const __half* __restrict__ simh, const float* __restrict__ embf,
    const u32* __restrict__ kmax32, int2* __restrict__ compact) {
  const int row = blockIdx.x;
  const int t = threadIdx.x;
  const int lane = t & 63;
  const int wave = t >> 6;

  __shared__ u32 hist[257];
  __shared__ int bcol[BANDCAP];
  __shared__ u32 bkey[BANDCAP];
  __shared__ float bex[BANDCAP];
  __shared__ int outidx_s[KSEL];
  __shared__ float outval_s[KSEL];
  __shared__ int cnts[2];          // [0]=band count, [1]=out count
  __shared__ u32 sh_lo, sh_hi, sh_need;
  __shared__ int sh_state;         // 0=escalate, 1=descend, 2=done

  const int segBase = (row >> 11) << 11;

  // load row once: 3 uint4/thread, pack keys in place (12 VGPRs total)
  u32 pk[12];
  {
    const uint4* src = reinterpret_cast<const uint4*>(simh + (size_t)row * NVALID);
    const uint4 a = src[t], b = src[256 + t], c = src[512 + t];
    pk[0] = packkeys(a.x); pk[1] = packkeys(a.y);
    pk[2] = packkeys(a.z); pk[3] = packkeys(a.w);
    pk[4] = packkeys(b.x); pk[5] = packkeys(b.y);
    pk[6] = packkeys(b.z); pk[7] = packkeys(b.w);
    pk[8] = packkeys(c.x); pk[9] = packkeys(c.y);
    pk[10] = packkeys(c.z); pk[11] = packkeys(c.w);
  }
#define KEY(v) ((pk[(v) >> 1] >> (((v) & 1) * 16)) & 0xFFFFu)
#define COL(v) ((((((v) >> 3) * 256) + t) << 3) + ((v) & 7))

  if (t < KSEL) { outidx_s[t] = segBase; outval_s[t] = 0.0f; }
  if (t == 0) { cnts[0] = 0; cnts[1] = 0; }

  // row-max f16 key from gemm's f32-key accumulator (RTN monotone)
  u32 kmax16;
  {
    const u32 kk = kmax32[row];
    const u32 fb = (kk & 0x80000000u) ? (kk ^ 0x80000000u) : ~kk;
    const __half h = __float2half(__uint_as_float(fb));
    kmax16 = f16key((u32)__half_as_ushort(h));
  }

  // locate interval [binlo, binhi] containing the 31st-largest key.
  // tier0: 1-ulp bins over [kmax-255, kmax] -> exact k31 in one pass.
  u32 base = (kmax16 > 255u) ? kmax16 - 255u : 0u;
  u32 winTop = kmax16;
  u32 shift = 0;
  u32 need = KSEL;
  int tier = 0;
  for (int guard = 0; guard < 6; ++guard) {
    hist[t] = 0;
    if (t == 0) hist[256] = 0;
    __syncthreads();
#pragma unroll
    for (int v = 0; v < 24; ++v) {
      const u32 k = KEY(v);
      if (k >= base && k <= winTop) atomicAdd(&hist[(k - base) >> shift], 1u);
    }
    __syncthreads();
    if (wave == 0) {
      const int x = lane * 4;
      const u32 b0 = hist[x], b1 = hist[x + 1];
      const u32 b2 = hist[x + 2], b3 = hist[x + 3];
      const u32 tot = b0 + b1 + b2 + b3;
      u32 inc = tot;
#pragma unroll
      for (int off = 1; off < 64; off <<= 1) {
        const u32 vv = (u32)__shfl_down((int)inc, off, 64);
        if (lane + off < 64) inc += vv;
      }
      const u32 exc = inc - tot;
      const u32 g3 = exc, g2 = g3 + b3, g1 = g2 + b2, g0 = g1 + b1;
      int sel = -1;
      u32 gsel = 0;
      if (g3 < need && g3 + b3 >= need) { sel = x + 3; gsel = g3; }
      else if (g2 < need && g2 + b2 >= need) { sel = x + 2; gsel = g2; }
      else if (g1 < need && g1 + b1 >= need) { sel = x + 1; gsel = g1; }
      else if (g0 < need && g0 + b0 >= need) { sel = x;     gsel = g0; }
      const u64 bal = __ballot(sel >= 0);
      if (lane == 0 && bal == 0) sh_state = 0;  // escalate
      if (bal != 0) {
        const int srcl = (int)(__ffsll((unsigned long long)bal) - 1);
        sel  = __shfl(sel, srcl, 64);
        gsel = (u32)__shfl((int)gsel, srcl, 64);
        if (lane == 0) {
          const u32 blo = base + ((u32)sel << shift);
          const u32 bhi = min(blo + (1u << shift) - 1u, winTop);
          sh_lo = blo; sh_hi = bhi; sh_need = need - gsel;
          sh_state = (shift > 0) ? 1 : 2;
        }
      }
    }
    __syncthreads();
    const int st = sh_state;
    if (st == 2) break;
    if (st == 1) {  // descend into wide bin with 1-ulp bins
      base = sh_lo; winTop = sh_hi; shift = 0; need = sh_need;
    } else {        // escalate window
      ++tier;
      if (tier == 1) { base = (kmax16 > 2047u) ? kmax16 - 2047u : 0u; shift = 3; }
      else { base = 0u; shift = 8; }
      winTop = kmax16; need = KSEL;
    }
    __syncthreads();
  }
  const u32 binlo = sh_lo, binhi = sh_hi;
  const u32 hiK = binhi + BAND_ULP;
  const u32 loK = (binlo >= BAND_ULP) ? binlo - BAND_ULP : 0u;

  // classify from regs: emit H (f16 value), collect band cols+keys
#pragma unroll
  for (int v = 0; v < 24; ++v) {
    const u32 k = KEY(v);
    if (k > hiK) {
      const int slot = atomicAdd(&cnts[1], 1);
      const int i = COL(v);
      if (slot < KSEL) {
        outidx_s[slot] = (i < segBase) ? i : i + SEG_SIZE;
        outval_s[slot] = fmaxf(keyval(k), 0.0f);
      }
    } else if (k >= loK) {
      const int slot = atomicAdd(&cnts[0], 1);
      const int i = COL(v);
      if (slot < BANDCAP) {
        bcol[slot] = (i < segBase) ? i : i + SEG_SIZE;
        bkey[slot] = k;
      }
    }
  }
  __syncthreads();
  const int nH = min(cnts[1], KSEL);
  const int slots = KSEL - nH;
  const int nB = min(cnts[0], BANDCAP);

  if (nB == slots) {
    // whole band is selected: no exact ordering needed
    if (t < nB) {
      const int slot = atomicAdd(&cnts[1], 1);
      if (slot < KSEL) {
        outidx_s[slot] = bcol[t];
        outval_s[slot] = fmaxf(keyval(bkey[t]), 0.0f);
      }
    }
  } else {
    // bit-exact np-sequential dots for band members (verified R6 rounding)
    if (t < nB) {
#pragma clang fp contract(off)
      const float4* g4 =
          reinterpret_cast<const float4*>(embf + (size_t)bcol[t] * DIM);
      const float4* e4 = reinterpret_cast<const float4*>(embf + (size_t)row * DIM);
      float acc = 0.0f;
      for (int k4 = 0; k4 < DIM / 4; ++k4) {
        const float4 a = e4[k4];
        const float4 b = g4[k4];
        acc = acc + a.x * b.x;
        acc = acc + a.y * b.y;
        acc = acc + a.z * b.z;
        acc = acc + a.w * b.w;
      }
      bex[t] = acc;
    }
    __syncthreads();
    // band rank (exact desc, col asc); winners fill remaining slots
    if (t < nB) {
      const float ev = bex[t];
      const int ec = bcol[t];
      int r = 0;
      for (int j = 0; j < nB; ++j) {
        const float oj = bex[j];
        const int cj = bcol[j];
        if (oj > ev || (oj == ev && cj < ec)) r++;
      }
      if (r < slots) {
        const int slot = atomicAdd(&cnts[1], 1);
        if (slot < KSEL) { outidx_s[slot] = ec; outval_s[slot] = fmaxf(ev, 0.0f); }
      }
    }
  }
  __syncthreads();
  if (t < KSEL)
    compact[(size_t)row * KSEL + t] =
        make_int2(outidx_s[t], __float_as_int(outval_s[t]));
#undef KEY
#undef COL
}

// ---------------------------------------------------------------------------
// Kernel 4a: barrier-free grid-stride zero of the full output (max BW).
// ---------------------------------------------------------------------------
__global__ __launch_bounds__(256) void zero_kernel(float4* __restrict__ out4) {
  const size_t total = (size_t)N_NODES * N_NODES / 4;
  const float4 z = make_float4(0.f, 0.f, 0.f, 0.f);
  for (size_t i = (size_t)blockIdx.x * 256 + threadIdx.x; i < total;
       i += (size_t)gridDim.x * 256)
    out4[i] = z;
}

// ---------------------------------------------------------------------------
// Kernel 4b: scatter 31 values per row (8192*31 entries).
// ---------------------------------------------------------------------------
__global__ __launch_bounds__(256) void scatter_kernel(
    const int2* __restrict__ compact, float* __restrict__ out) {
  const int gid = blockIdx.x * 256 + threadIdx.x;
  if (gid >= N_NODES * KSEL) return;
  const int row = gid / KSEL;
  const int2 e = compact[gid];
  out[(size_t)row * N_NODES + e.x] = __int_as_float(e.y);
}

// ---------------------------------------------------------------------------
extern "C" void kernel_launch(void* const* d_in, const int* in_sizes, int n_in,
                              void* d_out, int out_size, void* d_ws, size_t ws_size,
                              hipStream_t stream) {
  const float* feat = (const float*)d_in[0];
  const float* w0 = (const float*)d_in[1];
  const float* w1 = (const float*)d_in[2];
  float* out = (float*)d_out;

  u16* embh = (u16*)d_ws;                                           // [0,8MiB)
  float* embf = (float*)((char*)d_ws + (size_t)N_NODES * DIM * 2);  // [8,24MiB)
  u32* kmax32 = (u32*)((char*)d_ws + (size_t)24 * 1024 * 1024);     // 32 KiB
  int2* compact = (int2*)d_ws;                                      // reuses embh
  __half* simh = (__half*)d_out;                                    // 100 MB in d_out

  prep_kernel<<<N_NODES, 256, 0, stream>>>(feat, w0, w1, embh, embf, kmax32);
  dim3 grid(48, 64);
  gemm_kernel<<<grid, 64 * 4, 0, stream>>>(embh, simh, kmax32);
  select_kernel<<<N_NODES, 256, 0, stream>>>(simh, embf, kmax32, compact);
  zero_kernel<<<2048, 256, 0, stream>>>((float4*)out);
  scatter_kernel<<<(N_NODES * KSEL + 255) / 256, 256, 0, stream>>>(compact, out);
}

// Round 21
// 225.937 us; speedup vs baseline: 1.1745x; 1.1438x over previous
//
#include <hip/hip_runtime.h>
#include <hip/hip_bf16.h>
#include <hip/hip_fp16.h>
#include <math.h>

typedef unsigned short u16;
typedef unsigned int u32;
typedef unsigned long long u64;
typedef __attribute__((ext_vector_type(8))) short bf16x8;
typedef __attribute__((ext_vector_type(4))) float f32x4;

#define N_NODES 8192
#define DIM 512
#define KSEL 31
#define BANDCAP 128
#define SEG_SIZE 2048
#define NVALID 6144   // cross-segment columns per row
#define BAND_ULP 8    // band half-width in f16 ulps (R14..R18-verified)

// monotone 16-bit key from f16 bits (larger key <=> larger value)
__device__ __forceinline__ u32 f16key(u32 h) {
  return (h & 0x8000u) ? (0xFFFFu & ~h) : (h | 0x8000u);
}
__device__ __forceinline__ u32 packkeys(u32 w) {  // two f16 -> two keys
  return f16key(w & 0xFFFFu) | (f16key(w >> 16) << 16);
}
__device__ __forceinline__ float keyval(u32 k) {
  const u16 raw = (k & 0x8000u) ? (u16)(k ^ 0x8000u) : (u16)(~k & 0xFFFFu);
  __half_raw hr; hr.x = raw;
  return __half2float(__half(hr));
}

#define GLD_LDS16(g, l)                                        \
  __builtin_amdgcn_global_load_lds(                            \
      (const __attribute__((address_space(1))) void*)(g),      \
      (__attribute__((address_space(3))) void*)(l), 16, 0, 0)

// ---------------------------------------------------------------------------
// Kernel 1: emb replicating numpy-f32 bit-exactly (verified R6). Also zeroes
// the per-row kmax accumulator used by the gemm epilogue.
// ---------------------------------------------------------------------------
__global__ __launch_bounds__(256) void prep_kernel(
    const float* __restrict__ feat, const float* __restrict__ w0,
    const float* __restrict__ w1, u16* __restrict__ embh,
    float* __restrict__ embf, u32* __restrict__ kmax32) {
#pragma clang fp contract(off)
  const int row = blockIdx.x;
  const int t = threadIdx.x;
  __shared__ float hs[DIM];
  __shared__ float partial[32];
  __shared__ float rinv_sh;

  const float2 x = *reinterpret_cast<const float2*>(feat + (size_t)row * DIM + t * 2);
  const float2 a = *reinterpret_cast<const float2*>(w0 + t * 2);
  const float2 b = *reinterpret_cast<const float2*>(w1 + t * 2);
  const float h0 = fmaxf(x.x * a.x, 0.0f) * b.x;
  const float h1 = fmaxf(x.y * a.y, 0.0f) * b.y;
  hs[t * 2] = h0;
  hs[t * 2 + 1] = h1;
  if (t == 0) kmax32[row] = 0u;
  __syncthreads();

  if (t < 32) {
    const int base = (t >> 3) * 128 + (t & 7);
    float v = hs[base];
    float acc = v * v;
    for (int i = 1; i < 16; ++i) {
      v = hs[base + 8 * i];
      const float vv = v * v;
      acc = acc + vv;
    }
    partial[t] = acc;
  }
  __syncthreads();
  if (t == 0) {
    float B[4];
    for (int blk = 0; blk < 4; ++blk) {
      const float* p = &partial[blk * 8];
      B[blk] = ((p[0] + p[1]) + (p[2] + p[3])) + ((p[4] + p[5]) + (p[6] + p[7]));
    }
    const float s = (B[0] + B[1]) + (B[2] + B[3]);
    const float sp = s + 1e-24f;
    const float qf = (float)sqrt((double)sp);
    rinv_sh = (float)(1.0 / (double)qf);
  }
  __syncthreads();
  const float rinv = rinv_sh;
  const float e0 = h0 * rinv;
  const float e1 = h1 * rinv;
  *reinterpret_cast<float2*>(embf + (size_t)row * DIM + t * 2) = make_float2(e0, e1);
  __hip_bfloat162 bb;
  bb.x = __float2bfloat16(e0);
  bb.y = __float2bfloat16(e1);
  *reinterpret_cast<__hip_bfloat162*>(embh + (size_t)row * DIM + t * 2) = bb;
}

// ---------------------------------------------------------------------------
// Kernel 2: SYMMETRIC ranking sim (bf16 MFMA) -> f16, packed cross-seg cols.
// Only tiles with colTile > rowTile compute; each writes its tile normally
// AND transposed (sim is exactly symmetric: np's k-chain commutes in the
// product, and our MFMA accumulation order is operand-swap invariant).
// Epilogue feeds per-row kmax for BOTH row sets (row-max + col-max).
// ---------------------------------------------------------------------------
__global__ __launch_bounds__(256) void gemm_kernel(const u16* __restrict__ embh,
                                                   __half* __restrict__ simh,
                                                   u32* __restrict__ kmax32) {
  const int tid = threadIdx.x;
  const int lane = tid & 63;
  const int wave = tid >> 6;
  const int wm = wave >> 1;
  const int wn = wave & 1;
  const int rowTile = blockIdx.y;
  const int segTileBase = (rowTile >> 4) << 4;
  const int cT = blockIdx.x;
  const int colTile = cT < segTileBase ? cT : cT + 16;
  if (colTile <= rowTile) return;  // symmetric half only
  const int row0 = rowTile * 128;
  const int col0 = colTile * 128;

  __shared__ u16 As[128][64];
  __shared__ u16 Bs[128][64];
  f32x4 acc[4][4] = {};

  for (int k0 = 0; k0 < DIM; k0 += 64) {
#pragma unroll
    for (int i = 0; i < 4; ++i) {
      const int flat = i * 256 + tid;
      const int r = flat >> 3;
      const int c = (flat & 7) * 8;
      GLD_LDS16(embh + (size_t)(row0 + r) * DIM + k0 + c, &As[r][c]);
      GLD_LDS16(embh + (size_t)(col0 + r) * DIM + k0 + c, &Bs[r][c]);
    }
    __syncthreads();
#pragma unroll
    for (int kk = 0; kk < 2; ++kk) {
      bf16x8 afr[4], bfr[4];
      const int koff = kk * 32 + (lane >> 4) * 8;
      const int rsel = lane & 15;
#pragma unroll
      for (int m = 0; m < 4; ++m)
        afr[m] = *reinterpret_cast<const bf16x8*>(&As[wm * 64 + m * 16 + rsel][koff]);
#pragma unroll
      for (int n = 0; n < 4; ++n)
        bfr[n] = *reinterpret_cast<const bf16x8*>(&Bs[wn * 64 + n * 16 + rsel][koff]);
#pragma unroll
      for (int m = 0; m < 4; ++m)
#pragma unroll
        for (int n = 0; n < 4; ++n)
          acc[m][n] = __builtin_amdgcn_mfma_f32_16x16x32_bf16(afr[m], bfr[n],
                                                              acc[m][n], 0, 0, 0);
    }
    __syncthreads();
  }

  // normal write: rows row0+.., packed col cT*128+..
#pragma unroll
  for (int m = 0; m < 4; ++m)
#pragma unroll
    for (int n = 0; n < 4; ++n)
#pragma unroll
      for (int j = 0; j < 4; ++j) {
        const int r = row0 + wm * 64 + m * 16 + (lane >> 4) * 4 + j;
        const int pcol = cT * 128 + wn * 64 + n * 16 + (lane & 15);
        simh[(size_t)r * NVALID + pcol] = __float2half(acc[m][n][j]);
      }
  // transposed write: rows col0+.., packed col of global col row0+..
  // (rows of colTile's segment never contain row0's segment: radj constant)
  {
    const int segBaseC = (col0 >> 11) << 11;
    const int radj = (row0 < segBaseC) ? 0 : -SEG_SIZE;
#pragma unroll
    for (int m = 0; m < 4; ++m)
#pragma unroll
      for (int n = 0; n < 4; ++n) {
        const int c = col0 + wn * 64 + n * 16 + (lane & 15);
        const int rbase = row0 + wm * 64 + m * 16 + (lane >> 4) * 4;
        const __half h0 = __float2half(acc[m][n][0]);
        const __half h1 = __float2half(acc[m][n][1]);
        const __half h2 = __float2half(acc[m][n][2]);
        const __half h3 = __float2half(acc[m][n][3]);
        uint2 pkd;
        pkd.x = (u32)__half_as_ushort(h0) | ((u32)__half_as_ushort(h1) << 16);
        pkd.y = (u32)__half_as_ushort(h2) | ((u32)__half_as_ushort(h3) << 16);
        *reinterpret_cast<uint2*>(&simh[(size_t)c * NVALID + radj + rbase]) = pkd;
      }
  }
  // row-side kmax (rows row0+..): max over this tile's 128 cols
#pragma unroll
  for (int m = 0; m < 4; ++m) {
#pragma unroll
    for (int j = 0; j < 4; ++j) {
      float vmax = fmaxf(fmaxf(acc[m][0][j], acc[m][1][j]),
                         fmaxf(acc[m][2][j], acc[m][3][j]));
#pragma unroll
      for (int off = 1; off < 16; off <<= 1)
        vmax = fmaxf(vmax, __shfl_xor(vmax, off, 64));
      if ((lane & 15) == 0) {
        const int r = row0 + wm * 64 + m * 16 + (lane >> 4) * 4 + j;
        const u32 b = __float_as_uint(vmax);
        const u32 kk = (b & 0x80000000u) ? ~b : (b | 0x80000000u);
        atomicMax(&kmax32[r], kk);
      }
    }
  }
  // col-side kmax (rows col0+..): max over this tile's 128 rows
#pragma unroll
  for (int n = 0; n < 4; ++n) {
    float cmax = acc[0][n][0];
#pragma unroll
    for (int m = 0; m < 4; ++m)
#pragma unroll
      for (int j = 0; j < 4; ++j) cmax = fmaxf(cmax, acc[m][n][j]);
    cmax = fmaxf(cmax, __shfl_xor(cmax, 16, 64));
    cmax = fmaxf(cmax, __shfl_xor(cmax, 32, 64));
    if ((lane >> 4) == 0) {
      const int c = col0 + wn * 64 + n * 16 + (lane & 15);
      const u32 b = __float_as_uint(cmax);
      const u32 kk = (b & 0x80000000u) ? ~b : (b | 0x80000000u);
      atomicMax(&kmax32[c], kk);
    }
  }
}

// ---------------------------------------------------------------------------
// Kernel 3: block-per-row select, ONE-PASS histogram: 16-ulp bins over
// [kmax-4095, kmax] (k31 sits ~350 ulps below kmax -> window always covers;
// escalation only for degenerate rows). Interval sandwich (R17-verified):
// H = {k > binhi+8} emits f16 value; band [binlo-8,binhi+8] resolved by
// bit-exact np-sequential dots (verified R6); nB==slots skips dots.
// ---------------------------------------------------------------------------
__global__ __launch_bounds__(256) void select_kernel(
    const __half* __restrict__ simh, const float* __restrict__ embf,
    const u32* __restrict__ kmax32, int2* __restrict__ compact) {
  const int row = blockIdx.x;
  const int t = threadIdx.x;
  const int lane = t & 63;
  const int wave = t >> 6;

  __shared__ u32 hist[257];
  __shared__ int bcol[BANDCAP];
  __shared__ u32 bkey[BANDCAP];
  __shared__ float bex[BANDCAP];
  __shared__ int outidx_s[KSEL];
  __shared__ float outval_s[KSEL];
  __shared__ int cnts[2];
  __shared__ u32 sh_lo, sh_hi, sh_need;
  __shared__ int sh_state;  // 0=escalate, 1=descend, 2=done

  const int segBase = (row >> 11) << 11;

  // load row once: 3 uint4/thread, pack keys in place (12 VGPRs total)
  u32 pk[12];
  {
    const uint4* src = reinterpret_cast<const uint4*>(simh + (size_t)row * NVALID);
    const uint4 a = src[t], b = src[256 + t], c = src[512 + t];
    pk[0] = packkeys(a.x); pk[1] = packkeys(a.y);
    pk[2] = packkeys(a.z); pk[3] = packkeys(a.w);
    pk[4] = packkeys(b.x); pk[5] = packkeys(b.y);
    pk[6] = packkeys(b.z); pk[7] = packkeys(b.w);
    pk[8] = packkeys(c.x); pk[9] = packkeys(c.y);
    pk[10] = packkeys(c.z); pk[11] = packkeys(c.w);
  }
#define KEY(v) ((pk[(v) >> 1] >> (((v) & 1) * 16)) & 0xFFFFu)
#define COL(v) ((((((v) >> 3) * 256) + t) << 3) + ((v) & 7))

  if (t < KSEL) { outidx_s[t] = segBase; outval_s[t] = 0.0f; }
  if (t == 0) { cnts[0] = 0; cnts[1] = 0; }

  // row-max f16 key from gemm's f32-key accumulator (RTN monotone)
  u32 kmax16;
  {
    const u32 kk = kmax32[row];
    const u32 fb = (kk & 0x80000000u) ? (kk ^ 0x80000000u) : ~kk;
    const __half h = __float2half(__uint_as_float(fb));
    kmax16 = f16key((u32)__half_as_ushort(h));
  }

  // locate 16-ulp interval [binlo, binhi] containing the 31st-largest key
  u32 base = (kmax16 > 4095u) ? kmax16 - 4095u : 0u;
  u32 winTop = kmax16;
  u32 shift = 4;
  u32 need = KSEL;
  for (int guard = 0; guard < 4; ++guard) {
    hist[t] = 0;
    if (t == 0) hist[256] = 0;
    __syncthreads();
#pragma unroll
    for (int v = 0; v < 24; ++v) {
      const u32 k = KEY(v);
      if (k >= base && k <= winTop) atomicAdd(&hist[(k - base) >> shift], 1u);
    }
    __syncthreads();
    if (wave == 0) {
      const int x = lane * 4;
      const u32 b0 = hist[x], b1 = hist[x + 1];
      const u32 b2 = hist[x + 2], b3 = hist[x + 3];
      const u32 tot = b0 + b1 + b2 + b3;
      u32 inc = tot;
#pragma unroll
      for (int off = 1; off < 64; off <<= 1) {
        const u32 vv = (u32)__shfl_down((int)inc, off, 64);
        if (lane + off < 64) inc += vv;
      }
      const u32 exc = inc - tot;
      const u32 g3 = exc, g2 = g3 + b3, g1 = g2 + b2, g0 = g1 + b1;
      int sel = -1;
      u32 gsel = 0;
      if (g3 < need && g3 + b3 >= need) { sel = x + 3; gsel = g3; }
      else if (g2 < need && g2 + b2 >= need) { sel = x + 2; gsel = g2; }
      else if (g1 < need && g1 + b1 >= need) { sel = x + 1; gsel = g1; }
      else if (g0 < need && g0 + b0 >= need) { sel = x;     gsel = g0; }
      const u64 bal = __ballot(sel >= 0);
      if (lane == 0 && bal == 0) sh_state = 0;
      if (bal != 0) {
        const int srcl = (int)(__ffsll((unsigned long long)bal) - 1);
        sel  = __shfl(sel, srcl, 64);
        gsel = (u32)__shfl((int)gsel, srcl, 64);
        if (lane == 0) {
          const u32 blo = base + ((u32)sel << shift);
          const u32 bhi = min(blo + (1u << shift) - 1u, winTop);
          sh_lo = blo; sh_hi = bhi; sh_need = need - gsel;
          sh_state = (shift > 4) ? 1 : 2;
        }
      }
    }
    __syncthreads();
    const int st = sh_state;
    if (st == 2) break;
    if (st == 1) {  // descend into 256-ulp bin with 16-ulp bins
      base = sh_lo; winTop = sh_hi; shift = 4; need = sh_need;
    } else {        // degenerate row: full-range 256-ulp bins
      base = 0u; winTop = kmax16; shift = 8; need = KSEL;
    }
    __syncthreads();
  }
  const u32 binlo = sh_lo, binhi = sh_hi;
  const u32 hiK = binhi + BAND_ULP;
  const u32 loK = (binlo >= BAND_ULP) ? binlo - BAND_ULP : 0u;

  // classify from regs: emit H (f16 value), collect band cols+keys
#pragma unroll
  for (int v = 0; v < 24; ++v) {
    const u32 k = KEY(v);
    if (k > hiK) {
      const int slot = atomicAdd(&cnts[1], 1);
      const int i = COL(v);
      if (slot < KSEL) {
        outidx_s[slot] = (i < segBase) ? i : i + SEG_SIZE;
        outval_s[slot] = fmaxf(keyval(k), 0.0f);
      }
    } else if (k >= loK) {
      const int slot = atomicAdd(&cnts[0], 1);
      const int i = COL(v);
      if (slot < BANDCAP) {
        bcol[slot] = (i < segBase) ? i : i + SEG_SIZE;
        bkey[slot] = k;
      }
    }
  }
  __syncthreads();
  const int nH = min(cnts[1], KSEL);
  const int slots = KSEL - nH;
  const int nB = min(cnts[0], BANDCAP);

  if (nB == slots) {
    if (t < nB) {
      const int slot = atomicAdd(&cnts[1], 1);
      if (slot < KSEL) {
        outidx_s[slot] = bcol[t];
        outval_s[slot] = fmaxf(keyval(bkey[t]), 0.0f);
      }
    }
  } else {
    // bit-exact np-sequential dots for band members (verified R6 rounding)
    if (t < nB) {
#pragma clang fp contract(off)
      const float4* g4 =
          reinterpret_cast<const float4*>(embf + (size_t)bcol[t] * DIM);
      const float4* e4 = reinterpret_cast<const float4*>(embf + (size_t)row * DIM);
      float acc = 0.0f;
      for (int k4 = 0; k4 < DIM / 4; ++k4) {
        const float4 a = e4[k4];
        const float4 b = g4[k4];
        acc = acc + a.x * b.x;
        acc = acc + a.y * b.y;
        acc = acc + a.z * b.z;
        acc = acc + a.w * b.w;
      }
      bex[t] = acc;
    }
    __syncthreads();
    if (t < nB) {
      const float ev = bex[t];
      const int ec = bcol[t];
      int r = 0;
      for (int j = 0; j < nB; ++j) {
        const float oj = bex[j];
        const int cj = bcol[j];
        if (oj > ev || (oj == ev && cj < ec)) r++;
      }
      if (r < slots) {
        const int slot = atomicAdd(&cnts[1], 1);
        if (slot < KSEL) { outidx_s[slot] = ec; outval_s[slot] = fmaxf(ev, 0.0f); }
      }
    }
  }
  __syncthreads();
  if (t < KSEL)
    compact[(size_t)row * KSEL + t] =
        make_int2(outidx_s[t], __float_as_int(outval_s[t]));
#undef KEY
#undef COL
}

// ---------------------------------------------------------------------------
// Kernel 4: streaming writer — zero full row, scatter 31 values.
// ---------------------------------------------------------------------------
__global__ __launch_bounds__(256) void write_kernel(
    const int2* __restrict__ compact, float* __restrict__ out) {
  const int row = blockIdx.x;
  const int t = threadIdx.x;
  __shared__ int sidx[KSEL];
  __shared__ float sval[KSEL];
  if (t < KSEL) {
    const int2 e = compact[(size_t)row * KSEL + t];
    sidx[t] = e.x;
    sval[t] = __int_as_float(e.y);
  }
  float* orow = out + (size_t)row * N_NODES;
  const float4 zero4 = make_float4(0.f, 0.f, 0.f, 0.f);
  __syncthreads();
#pragma unroll
  for (int i = 0; i < 8; ++i)
    reinterpret_cast<float4*>(orow)[i * 256 + t] = zero4;
  __syncthreads();
  if (t < KSEL) orow[sidx[t]] = sval[t];
}

// ---------------------------------------------------------------------------
extern "C" void kernel_launch(void* const* d_in, const int* in_sizes, int n_in,
                              void* d_out, int out_size, void* d_ws, size_t ws_size,
                              hipStream_t stream) {
  const float* feat = (const float*)d_in[0];
  const float* w0 = (const float*)d_in[1];
  const float* w1 = (const float*)d_in[2];
  float* out = (float*)d_out;

  u16* embh = (u16*)d_ws;                                           // [0,8MiB)
  float* embf = (float*)((char*)d_ws + (size_t)N_NODES * DIM * 2);  // [8,24MiB)
  u32* kmax32 = (u32*)((char*)d_ws + (size_t)24 * 1024 * 1024);     // 32 KiB
  int2* compact = (int2*)d_ws;                                      // reuses embh
  __half* simh = (__half*)d_out;                                    // 100 MB in d_out

  prep_kernel<<<N_NODES, 256, 0, stream>>>(feat, w0, w1, embh, embf, kmax32);
  dim3 grid(48, 64);
  gemm_kernel<<<grid, 256, 0, stream>>>(embh, simh, kmax32);
  select_kernel<<<N_NODES, 256, 0, stream>>>(simh, embf, kmax32, compact);
  write_kernel<<<N_NODES, 256, 0, stream>>>(compact, out);
}